// Round 2
// baseline (227.491 us; speedup 1.0000x reference)
//
#include <hip/hip_runtime.h>
#include <hip/hip_bf16.h>
#include <math.h>

// Problem constants: B=8, C=64, H=256, W=256
static constexpr int kC = 64;
static constexpr int kH = 256;
static constexpr int kW = 256;
static constexpr int kPlane = kH * kW;   // 65536

// Fixed stencils (same normalization as reference)
__constant__ float K_SX[9]  = {-0.125f, 0.0f, 0.125f,  -0.25f, 0.0f, 0.25f,  -0.125f, 0.0f, 0.125f};
__constant__ float K_SY[9]  = {-0.125f, -0.25f, -0.125f,  0.0f, 0.0f, 0.0f,  0.125f, 0.25f, 0.125f};
__constant__ float K_LAP[9] = {0.0f, -1.0f/6.0f, 0.0f,  -1.0f/6.0f, 4.0f/6.0f, -1.0f/6.0f,  0.0f, -1.0f/6.0f, 0.0f};
__constant__ float K_CS[9]  = {-1.0f/9.0f, -1.0f/9.0f, -1.0f/9.0f,  -1.0f/9.0f, 8.0f/9.0f, -1.0f/9.0f,  -1.0f/9.0f, -1.0f/9.0f, -1.0f/9.0f};

// -------- Kernel A: partial global-average-pool (4 blocks per plane) --------
__global__ __launch_bounds__(256) void pool_kernel(const float* __restrict__ x,
                                                   float* __restrict__ partial) {
    const int blk = blockIdx.x;            // 0..2047
    const int bc  = blk >> 2;
    const int q   = blk & 3;
    const float4* p = (const float4*)(x + (size_t)bc * kPlane) + q * 4096;
    float s = 0.0f;
    for (int i = threadIdx.x; i < 4096; i += 256) {
        float4 v = p[i];
        s += (v.x + v.y) + (v.z + v.w);
    }
    for (int off = 32; off; off >>= 1) s += __shfl_down(s, off);
    __shared__ float red[4];
    if ((threadIdx.x & 63) == 0) red[threadIdx.x >> 6] = s;
    __syncthreads();
    if (threadIdx.x == 0) partial[blk] = red[0] + red[1] + red[2] + red[3];
}

// -- Kernel B: SE attention MLP + combined 3x3 kernels + fus_w transpose ----
__global__ __launch_bounds__(256) void att_wc_kernel(
    const float* __restrict__ partial,  // [512][4]
    const float* __restrict__ idg_w,    // [64][9]
    const float* __restrict__ van_w,    // [64][9]
    const float* __restrict__ w1,       // [16][64]
    const float* __restrict__ b1,       // [16]
    const float* __restrict__ w2,       // [384][16]
    const float* __restrict__ b2,       // [384]
    const float* __restrict__ fus_w,    // [64][64] (o,c)
    float* __restrict__ wc_out,         // [8][64][9]
    float* __restrict__ fus_wT)         // [64][64] (c,o)
{
    __shared__ float spool[512];
    __shared__ float sh[8][16];
    __shared__ float satt[8 * 384];
    const int t = threadIdx.x;

    for (int i = t; i < 512; i += 256)
        spool[i] = (partial[4 * i] + partial[4 * i + 1] + partial[4 * i + 2] + partial[4 * i + 3])
                   * (1.0f / (float)kPlane);
    __syncthreads();

    if (t < 128) {
        const int b = t >> 4, j = t & 15;
        float acc = b1[j];
        const float* wr = w1 + j * 64;
        const float* pr = spool + b * 64;
        #pragma unroll 8
        for (int c = 0; c < 64; ++c) acc += wr[c] * pr[c];
        sh[b][j] = fmaxf(acc, 0.0f);
    }
    __syncthreads();

    for (int i = t; i < 8 * 384; i += 256) {
        const int b = i / 384, k = i - b * 384;
        float acc = b2[k];
        const float* wr = w2 + k * 16;
        #pragma unroll
        for (int j = 0; j < 16; ++j) acc += wr[j] * sh[b][j];
        satt[i] = 1.0f / (1.0f + expf(-acc));
    }
    __syncthreads();

    // Wc[b][c][k] = a0*idg + a1*CS + a2*SX + a3*SY + a4*LAP + a5*van
    for (int i = t; i < 8 * 64 * 9; i += 256) {
        const int b = i / 576;
        const int r = i - b * 576;
        const int c = r / 9;
        const int k = r - c * 9;
        const float* ab = satt + b * 384;
        float v = ab[0 * 64 + c] * idg_w[c * 9 + k]
                + ab[1 * 64 + c] * K_CS[k]
                + ab[2 * 64 + c] * K_SX[k]
                + ab[3 * 64 + c] * K_SY[k]
                + ab[4 * 64 + c] * K_LAP[k]
                + ab[5 * 64 + c] * van_w[c * 9 + k];
        wc_out[i] = v;
    }

    // transpose fusion weights once: fus_wT[c][o] = fus_w[o][c]
    for (int i = t; i < 4096; i += 256)
        fus_wT[(i & 63) * 64 + (i >> 6)] = fus_w[i];
}

// ------ Kernel C: fused depthwise(combined) conv + 1x1 fusion conv --------
// Tile: 32 (W) x 8 (H) = 256 px; block = 256 threads = 4 waves; 2 blocks/CU.
// Phase 1: each thread computes all 64 channels' dw-conv for ONE pixel
//          (weights via scalar loads: uniform address), writes s_dw[c][p].
// Phase 2: 64(o) x 256(px) fp32 GEMM over c, 8x8 register tile per thread
//          -> 4 ds_read_b128 per 64 FMA.
__global__ __launch_bounds__(256, 2) void fused_dw_mix_kernel(
    const float* __restrict__ x,       // [8][64][256][256]
    const float* __restrict__ wc,      // [8][64][9]
    const float* __restrict__ fus_wT,  // [64][64] (c,o)
    const float* __restrict__ fus_b,   // [64]
    float* __restrict__ out)           // [8][64][256][256]
{
    __shared__ float s_fw[64 * 64];    // [c][o]
    __shared__ float s_dw[64 * 256];   // [c][p]

    const int t  = threadIdx.x;
    const int b  = blockIdx.z;
    const int y0 = blockIdx.y * 8;
    const int x0 = blockIdx.x * 32;

    // stage fus_wT: coalesced read, stride-1 conflict-free write
    {
        const float4* src = (const float4*)fus_wT;
        float4* dst = (float4*)s_fw;
        #pragma unroll
        for (int k = 0; k < 4; ++k) dst[t + k * 256] = src[t + k * 256];
    }

    // ---------------- phase 1: depthwise conv into LDS ----------------
    const int px = t & 31;
    const int py = t >> 5;
    const int yy = y0 + py;
    const int xx = x0 + px;
    const float* xb  = x + (size_t)b * (kC * kPlane);
    const float* wcb = wc + b * 576;   // uniform address -> scalar loads
    const bool interior = (y0 >= 1) && (y0 + 8 <= 255) && (x0 >= 1) && (x0 + 32 <= 255);

    if (interior) {
        #pragma unroll 2
        for (int c = 0; c < 64; ++c) {
            const float* w9 = wcb + c * 9;
            const float* xc = xb + (size_t)c * kPlane + yy * kW + xx;
            float acc = w9[0] * xc[-kW - 1] + w9[1] * xc[-kW] + w9[2] * xc[-kW + 1]
                      + w9[3] * xc[-1]      + w9[4] * xc[0]   + w9[5] * xc[1]
                      + w9[6] * xc[kW - 1]  + w9[7] * xc[kW]  + w9[8] * xc[kW + 1];
            s_dw[c * 256 + t] = acc;
        }
    } else {
        for (int c = 0; c < 64; ++c) {
            const float* w9 = wcb + c * 9;
            const float* xc = xb + (size_t)c * kPlane;
            float acc = 0.0f;
            #pragma unroll
            for (int dy = -1; dy <= 1; ++dy) {
                #pragma unroll
                for (int dx = -1; dx <= 1; ++dx) {
                    const int Y = yy + dy, X = xx + dx;
                    const float v = ((unsigned)Y < (unsigned)kH && (unsigned)X < (unsigned)kW)
                                        ? xc[Y * kW + X] : 0.0f;
                    acc += w9[(dy + 1) * 3 + (dx + 1)] * v;
                }
            }
            s_dw[c * 256 + t] = acc;
        }
    }
    __syncthreads();

    // ------------- phase 2: 64x256 GEMM (o x p over c), 8x8/thread -------------
    const int to = t >> 5;   // 0..7  -> o block of 8
    const int tp = t & 31;   // 0..31 -> p block of 8
    float acc[8][8];
    #pragma unroll
    for (int i = 0; i < 8; ++i)
        #pragma unroll
        for (int j = 0; j < 8; ++j) acc[i][j] = 0.0f;

    const float4* A = (const float4*)s_fw;   // 16 float4 per c-row
    const float4* D = (const float4*)s_dw;   // 64 float4 per c-row
    #pragma unroll 2
    for (int c = 0; c < 64; ++c) {
        const float4 a0 = A[c * 16 + to * 2];
        const float4 a1 = A[c * 16 + to * 2 + 1];
        const float4 d0 = D[c * 64 + tp * 2];
        const float4 d1 = D[c * 64 + tp * 2 + 1];
        const float av[8] = {a0.x, a0.y, a0.z, a0.w, a1.x, a1.y, a1.z, a1.w};
        const float dv[8] = {d0.x, d0.y, d0.z, d0.w, d1.x, d1.y, d1.z, d1.w};
        #pragma unroll
        for (int i = 0; i < 8; ++i)
            #pragma unroll
            for (int j = 0; j < 8; ++j)
                acc[i][j] += av[i] * dv[j];
    }

    // epilogue: bias + 2x float4 store per o (8 consecutive px in one row)
    const int p0  = tp * 8;
    const int opy = p0 >> 5;        // 0..7
    const int opx = p0 & 31;        // 0,8,16,24
    float* ob = out + (size_t)(b * kC) * kPlane + (size_t)(y0 + opy) * kW + (x0 + opx);
    #pragma unroll
    for (int i = 0; i < 8; ++i) {
        const int o = to * 8 + i;
        const float bias = fus_b[o];
        float4 v0, v1;
        v0.x = acc[i][0] + bias; v0.y = acc[i][1] + bias;
        v0.z = acc[i][2] + bias; v0.w = acc[i][3] + bias;
        v1.x = acc[i][4] + bias; v1.y = acc[i][5] + bias;
        v1.z = acc[i][6] + bias; v1.w = acc[i][7] + bias;
        float* po = ob + (size_t)o * kPlane;
        *(float4*)po = v0;
        *(float4*)(po + 4) = v1;
    }
}

extern "C" void kernel_launch(void* const* d_in, const int* in_sizes, int n_in,
                              void* d_out, int out_size, void* d_ws, size_t ws_size,
                              hipStream_t stream) {
    const float* x     = (const float*)d_in[0];
    const float* idg_w = (const float*)d_in[1];
    const float* van_w = (const float*)d_in[2];
    const float* w1    = (const float*)d_in[3];
    const float* b1    = (const float*)d_in[4];
    const float* w2    = (const float*)d_in[5];
    const float* b2    = (const float*)d_in[6];
    const float* fw    = (const float*)d_in[7];
    const float* fb    = (const float*)d_in[8];
    float* out = (float*)d_out;

    float* wsf    = (float*)d_ws;
    float* partial = wsf;              // 2048 floats
    float* wcbuf   = wsf + 2048;       // 4608 floats
    float* fwT     = wsf + 2048 + 4608;// 4096 floats

    hipLaunchKernelGGL(pool_kernel, dim3(2048), dim3(256), 0, stream, x, partial);
    hipLaunchKernelGGL(att_wc_kernel, dim3(1), dim3(256), 0, stream,
                       partial, idg_w, van_w, w1, b1, w2, b2, fw, wcbuf, fwT);
    hipLaunchKernelGGL(fused_dw_mix_kernel, dim3(kW / 32, kH / 8, 8), dim3(256), 0, stream,
                       x, wcbuf, fwT, fb, out);
}

// Round 3
// 144.522 us; speedup vs baseline: 1.5741x; 1.5741x over previous
//
#include <hip/hip_runtime.h>
#include <hip/hip_bf16.h>
#include <math.h>

// Problem constants: B=8, C=64, H=256, W=256
static constexpr int kC = 64;
static constexpr int kH = 256;
static constexpr int kW = 256;
static constexpr int kPlane = kH * kW;   // 65536

// Fixed stencils (same normalization as reference)
__constant__ float K_SX[9]  = {-0.125f, 0.0f, 0.125f,  -0.25f, 0.0f, 0.25f,  -0.125f, 0.0f, 0.125f};
__constant__ float K_SY[9]  = {-0.125f, -0.25f, -0.125f,  0.0f, 0.0f, 0.0f,  0.125f, 0.25f, 0.125f};
__constant__ float K_LAP[9] = {0.0f, -1.0f/6.0f, 0.0f,  -1.0f/6.0f, 4.0f/6.0f, -1.0f/6.0f,  0.0f, -1.0f/6.0f, 0.0f};
__constant__ float K_CS[9]  = {-1.0f/9.0f, -1.0f/9.0f, -1.0f/9.0f,  -1.0f/9.0f, 8.0f/9.0f, -1.0f/9.0f,  -1.0f/9.0f, -1.0f/9.0f, -1.0f/9.0f};

// -------- Kernel A: partial global-average-pool (4 blocks per plane) --------
__global__ __launch_bounds__(256) void pool_kernel(const float* __restrict__ x,
                                                   float* __restrict__ partial) {
    const int blk = blockIdx.x;            // 0..2047
    const int bc  = blk >> 2;
    const int q   = blk & 3;
    const float4* p = (const float4*)(x + (size_t)bc * kPlane) + q * 4096;
    float s = 0.0f;
    for (int i = threadIdx.x; i < 4096; i += 256) {
        float4 v = p[i];
        s += (v.x + v.y) + (v.z + v.w);
    }
    for (int off = 32; off; off >>= 1) s += __shfl_down(s, off);
    __shared__ float red[4];
    if ((threadIdx.x & 63) == 0) red[threadIdx.x >> 6] = s;
    __syncthreads();
    if (threadIdx.x == 0) partial[blk] = red[0] + red[1] + red[2] + red[3];
}

// -- Kernel B: SE attention MLP + combined 3x3 kernels + fus_w transpose ----
__global__ __launch_bounds__(256) void att_wc_kernel(
    const float* __restrict__ partial,  // [512][4]
    const float* __restrict__ idg_w,    // [64][9]
    const float* __restrict__ van_w,    // [64][9]
    const float* __restrict__ w1,       // [16][64]
    const float* __restrict__ b1,       // [16]
    const float* __restrict__ w2,       // [384][16]
    const float* __restrict__ b2,       // [384]
    const float* __restrict__ fus_w,    // [64][64] (o,c)
    float* __restrict__ wc_out,         // [8][64][9]
    float* __restrict__ fus_wT)         // [64][64] (c,o)
{
    __shared__ float spool[512];
    __shared__ float sh[8][16];
    __shared__ float satt[8 * 384];
    const int t = threadIdx.x;

    for (int i = t; i < 512; i += 256)
        spool[i] = (partial[4 * i] + partial[4 * i + 1] + partial[4 * i + 2] + partial[4 * i + 3])
                   * (1.0f / (float)kPlane);
    __syncthreads();

    if (t < 128) {
        const int b = t >> 4, j = t & 15;
        float acc = b1[j];
        const float* wr = w1 + j * 64;
        const float* pr = spool + b * 64;
        #pragma unroll 8
        for (int c = 0; c < 64; ++c) acc += wr[c] * pr[c];
        sh[b][j] = fmaxf(acc, 0.0f);
    }
    __syncthreads();

    for (int i = t; i < 8 * 384; i += 256) {
        const int b = i / 384, k = i - b * 384;
        float acc = b2[k];
        const float* wr = w2 + k * 16;
        #pragma unroll
        for (int j = 0; j < 16; ++j) acc += wr[j] * sh[b][j];
        satt[i] = 1.0f / (1.0f + expf(-acc));
    }
    __syncthreads();

    // Wc[b][c][k] = a0*idg + a1*CS + a2*SX + a3*SY + a4*LAP + a5*van
    for (int i = t; i < 8 * 64 * 9; i += 256) {
        const int b = i / 576;
        const int r = i - b * 576;
        const int c = r / 9;
        const int k = r - c * 9;
        const float* ab = satt + b * 384;
        float v = ab[0 * 64 + c] * idg_w[c * 9 + k]
                + ab[1 * 64 + c] * K_CS[k]
                + ab[2 * 64 + c] * K_SX[k]
                + ab[3 * 64 + c] * K_SY[k]
                + ab[4 * 64 + c] * K_LAP[k]
                + ab[5 * 64 + c] * van_w[c * 9 + k];
        wc_out[i] = v;
    }

    // transpose fusion weights once: fus_wT[c][o] = fus_w[o][c]
    for (int i = t; i < 4096; i += 256)
        fus_wT[(i & 63) * 64 + (i >> 6)] = fus_w[i];
}

// ------ Kernel C: fused depthwise(combined) conv + 1x1 fusion conv --------
// Tile: 32 (W) x 8 (H) = 256 px; block = 256 threads = 4 waves.
// c chunked 4x16: LDS = s_fw 16KB + s_dw 16KB = 32KB -> 4 blocks/CU.
// Phase 1 (per chunk): wave w computes channels chunk*16 + w*4 + {0..3},
//   each lane 4 consecutive px via 1 float4 + 2 guarded scalar loads per row.
// Phase 2 (per chunk): 64(o) x 256(px) GEMM over 16 c, 8x8 regs/thread.
__global__ __launch_bounds__(256, 4) void fused_dw_mix_kernel(
    const float* __restrict__ x,       // [8][64][256][256]
    const float* __restrict__ wc,      // [8][64][9]
    const float* __restrict__ fus_wT,  // [64][64] (c,o)
    const float* __restrict__ fus_b,   // [64]
    float* __restrict__ out)           // [8][64][256][256]
{
    __shared__ float s_fw[64 * 64];    // [c][o] 16 KB
    __shared__ float s_dw[16 * 256];   // [cic][p] 16 KB

    const int t  = threadIdx.x;
    const int b  = blockIdx.z;
    const int y0 = blockIdx.y * 8;
    const int x0 = blockIdx.x * 32;

    // stage fus_wT: coalesced read, stride-1 conflict-free write
    {
        const float4* src = (const float4*)fus_wT;
        float4* dst = (float4*)s_fw;
        #pragma unroll
        for (int k = 0; k < 4; ++k) dst[t + k * 256] = src[t + k * 256];
    }

    const int g   = t & 63;          // pixel group (lane id)
    const int wv  = t >> 6;          // wave id 0..3 (wave-uniform)
    const int py  = g >> 3;          // 0..7
    const int px4 = (g & 7) * 4;     // 0,4,...,28
    const int yy  = y0 + py;
    const int xx  = x0 + px4;

    const float* xb  = x + (size_t)b * (kC * kPlane);
    const float* wcb = wc + b * 576;

    const int to = t >> 5;           // 0..7  -> o block of 8
    const int tp = t & 31;           // 0..31 -> p block of 8
    float acc[8][8];
    #pragma unroll
    for (int i = 0; i < 8; ++i)
        #pragma unroll
        for (int j = 0; j < 8; ++j) acc[i][j] = 0.0f;

    const bool xlo = (xx > 0);       // can read column xx-1
    const bool xhi = (xx < 252);     // can read column xx+4

    for (int chunk = 0; chunk < 4; ++chunk) {
        __syncthreads();   // s_fw staged (chunk 0) / previous GEMM reads done

        // ---------------- phase 1: depthwise conv into LDS ----------------
        #pragma unroll 2
        for (int k = 0; k < 4; ++k) {
            const int c   = chunk * 16 + wv * 4 + k;
            const int cic = wv * 4 + k;
            const float* w9 = wcb + __builtin_amdgcn_readfirstlane(c) * 9;
            const float* xc = xb + (size_t)c * kPlane;
            float a0 = 0.0f, a1 = 0.0f, a2 = 0.0f, a3 = 0.0f;
            #pragma unroll
            for (int r = -1; r <= 1; ++r) {
                const int Y = yy + r;
                if ((unsigned)Y < (unsigned)kH) {
                    const float* rp = xc + Y * kW + xx;
                    const float  lm = xlo ? rp[-1] : 0.0f;
                    const float4 M  = *(const float4*)rp;
                    const float  rm = xhi ? rp[4] : 0.0f;
                    const float w0 = w9[(r + 1) * 3 + 0];
                    const float w1 = w9[(r + 1) * 3 + 1];
                    const float w2 = w9[(r + 1) * 3 + 2];
                    a0 += w0 * lm  + w1 * M.x + w2 * M.y;
                    a1 += w0 * M.x + w1 * M.y + w2 * M.z;
                    a2 += w0 * M.y + w1 * M.z + w2 * M.w;
                    a3 += w0 * M.z + w1 * M.w + w2 * rm;
                }
            }
            float4 v; v.x = a0; v.y = a1; v.z = a2; v.w = a3;
            *(float4*)&s_dw[cic * 256 + g * 4] = v;
        }
        __syncthreads();

        // ------------- phase 2: accumulate 16 c-iterations -------------
        const float4* A = (const float4*)s_fw + chunk * 16 * 16;  // [ci][16]
        const float4* D = (const float4*)s_dw;                    // [ci][64]
        #pragma unroll 2
        for (int ci = 0; ci < 16; ++ci) {
            const float4 a0 = A[ci * 16 + to * 2];
            const float4 a1 = A[ci * 16 + to * 2 + 1];
            const float4 d0 = D[ci * 64 + tp * 2];
            const float4 d1 = D[ci * 64 + tp * 2 + 1];
            const float av[8] = {a0.x, a0.y, a0.z, a0.w, a1.x, a1.y, a1.z, a1.w};
            const float dv[8] = {d0.x, d0.y, d0.z, d0.w, d1.x, d1.y, d1.z, d1.w};
            #pragma unroll
            for (int i = 0; i < 8; ++i)
                #pragma unroll
                for (int j = 0; j < 8; ++j)
                    acc[i][j] += av[i] * dv[j];
        }
    }

    // epilogue: bias + 2x float4 store per o (8 consecutive px in one row)
    const int p0  = tp * 8;
    const int opy = p0 >> 5;        // 0..7
    const int opx = p0 & 31;        // 0,8,16,24
    float* ob = out + (size_t)(b * kC) * kPlane + (size_t)(y0 + opy) * kW + (x0 + opx);
    #pragma unroll
    for (int i = 0; i < 8; ++i) {
        const int o = to * 8 + i;
        const float bias = fus_b[o];
        float4 v0, v1;
        v0.x = acc[i][0] + bias; v0.y = acc[i][1] + bias;
        v0.z = acc[i][2] + bias; v0.w = acc[i][3] + bias;
        v1.x = acc[i][4] + bias; v1.y = acc[i][5] + bias;
        v1.z = acc[i][6] + bias; v1.w = acc[i][7] + bias;
        float* po = ob + (size_t)o * kPlane;
        *(float4*)po = v0;
        *(float4*)(po + 4) = v1;
    }
}

extern "C" void kernel_launch(void* const* d_in, const int* in_sizes, int n_in,
                              void* d_out, int out_size, void* d_ws, size_t ws_size,
                              hipStream_t stream) {
    const float* x     = (const float*)d_in[0];
    const float* idg_w = (const float*)d_in[1];
    const float* van_w = (const float*)d_in[2];
    const float* w1    = (const float*)d_in[3];
    const float* b1    = (const float*)d_in[4];
    const float* w2    = (const float*)d_in[5];
    const float* b2    = (const float*)d_in[6];
    const float* fw    = (const float*)d_in[7];
    const float* fb    = (const float*)d_in[8];
    float* out = (float*)d_out;

    float* wsf     = (float*)d_ws;
    float* partial = wsf;               // 2048 floats
    float* wcbuf   = wsf + 2048;        // 4608 floats
    float* fwT     = wsf + 2048 + 4608; // 4096 floats

    hipLaunchKernelGGL(pool_kernel, dim3(2048), dim3(256), 0, stream, x, partial);
    hipLaunchKernelGGL(att_wc_kernel, dim3(1), dim3(256), 0, stream,
                       partial, idg_w, van_w, w1, b1, w2, b2, fw, wcbuf, fwT);
    hipLaunchKernelGGL(fused_dw_mix_kernel, dim3(kW / 32, kH / 8, 8), dim3(256), 0, stream,
                       x, wcbuf, fwT, fb, out);
}

// Round 4
// 126.214 us; speedup vs baseline: 1.8024x; 1.1451x over previous
//
#include <hip/hip_runtime.h>
#include <hip/hip_bf16.h>
#include <math.h>

// Problem constants: B=8, C=64, H=256, W=256
static constexpr int kC = 64;
static constexpr int kH = 256;
static constexpr int kW = 256;
static constexpr int kPlane = kH * kW;   // 65536

typedef __attribute__((ext_vector_type(8))) short bf16x8;
typedef __attribute__((ext_vector_type(4))) float f32x4;

__device__ __forceinline__ unsigned short f2bf(float f) {
    unsigned u = __builtin_bit_cast(unsigned, f);
    u += 0x7FFFu + ((u >> 16) & 1u);     // round-to-nearest-even
    return (unsigned short)(u >> 16);
}

// Fixed stencils (same normalization as reference)
__constant__ float K_SX[9]  = {-0.125f, 0.0f, 0.125f,  -0.25f, 0.0f, 0.25f,  -0.125f, 0.0f, 0.125f};
__constant__ float K_SY[9]  = {-0.125f, -0.25f, -0.125f,  0.0f, 0.0f, 0.0f,  0.125f, 0.25f, 0.125f};
__constant__ float K_LAP[9] = {0.0f, -1.0f/6.0f, 0.0f,  -1.0f/6.0f, 4.0f/6.0f, -1.0f/6.0f,  0.0f, -1.0f/6.0f, 0.0f};
__constant__ float K_CS[9]  = {-1.0f/9.0f, -1.0f/9.0f, -1.0f/9.0f,  -1.0f/9.0f, 8.0f/9.0f, -1.0f/9.0f,  -1.0f/9.0f, -1.0f/9.0f, -1.0f/9.0f};

// -------- Kernel A: partial global-average-pool (4 blocks per plane) --------
__global__ __launch_bounds__(256) void pool_kernel(const float* __restrict__ x,
                                                   float* __restrict__ partial) {
    const int blk = blockIdx.x;            // 0..2047
    const int bc  = blk >> 2;
    const int q   = blk & 3;
    const float4* p = (const float4*)(x + (size_t)bc * kPlane) + q * 4096;
    float s = 0.0f;
    for (int i = threadIdx.x; i < 4096; i += 256) {
        float4 v = p[i];
        s += (v.x + v.y) + (v.z + v.w);
    }
    for (int off = 32; off; off >>= 1) s += __shfl_down(s, off);
    __shared__ float red[4];
    if ((threadIdx.x & 63) == 0) red[threadIdx.x >> 6] = s;
    __syncthreads();
    if (threadIdx.x == 0) partial[blk] = red[0] + red[1] + red[2] + red[3];
}

// -- Kernel B: SE MLP + combined 3x3 kernels + MFMA A-fragment prepack ----
__global__ __launch_bounds__(256) void att_wc_kernel(
    const float* __restrict__ partial,  // [512][4]
    const float* __restrict__ idg_w,    // [64][9]
    const float* __restrict__ van_w,    // [64][9]
    const float* __restrict__ w1,       // [16][64]
    const float* __restrict__ b1,       // [16]
    const float* __restrict__ w2,       // [384][16]
    const float* __restrict__ b2,       // [384]
    const float* __restrict__ fus_w,    // [64][64] (o,c)
    float* __restrict__ wc_out,         // [8][64][9]
    unsigned short* __restrict__ apk)   // [2][4][64][8] bf16 A-fragments
{
    __shared__ float spool[512];
    __shared__ float sh[8][16];
    __shared__ float satt[8 * 384];
    const int t = threadIdx.x;

    for (int i = t; i < 512; i += 256)
        spool[i] = (partial[4 * i] + partial[4 * i + 1] + partial[4 * i + 2] + partial[4 * i + 3])
                   * (1.0f / (float)kPlane);
    __syncthreads();

    if (t < 128) {
        const int b = t >> 4, j = t & 15;
        float acc = b1[j];
        const float* wr = w1 + j * 64;
        const float* pr = spool + b * 64;
        #pragma unroll 8
        for (int c = 0; c < 64; ++c) acc += wr[c] * pr[c];
        sh[b][j] = fmaxf(acc, 0.0f);
    }
    __syncthreads();

    for (int i = t; i < 8 * 384; i += 256) {
        const int b = i / 384, k = i - b * 384;
        float acc = b2[k];
        const float* wr = w2 + k * 16;
        #pragma unroll
        for (int j = 0; j < 16; ++j) acc += wr[j] * sh[b][j];
        satt[i] = 1.0f / (1.0f + expf(-acc));
    }
    __syncthreads();

    // Wc[b][c][k] = a0*idg + a1*CS + a2*SX + a3*SY + a4*LAP + a5*van
    for (int i = t; i < 8 * 64 * 9; i += 256) {
        const int b = i / 576;
        const int r = i - b * 576;
        const int c = r / 9;
        const int k = r - c * 9;
        const float* ab = satt + b * 384;
        float v = ab[0 * 64 + c] * idg_w[c * 9 + k]
                + ab[1 * 64 + c] * K_CS[k]
                + ab[2 * 64 + c] * K_SX[k]
                + ab[3 * 64 + c] * K_SY[k]
                + ab[4 * 64 + c] * K_LAP[k]
                + ab[5 * 64 + c] * van_w[c * 9 + k];
        wc_out[i] = v;
    }

    // Prepack A-fragments for mfma_f32_16x16x32_bf16:
    // apk[kc][mb][lane][j] = bf16(fus_w[mb*16 + (lane&15)][kc*32 + (lane>>4)*8 + j])
    for (int i = t; i < 4096; i += 256) {
        const int j    = i & 7;
        const int lane = (i >> 3) & 63;
        const int mb   = (i >> 9) & 3;
        const int kc   = i >> 11;
        const int o = mb * 16 + (lane & 15);
        const int c = kc * 32 + (lane >> 4) * 8 + j;
        apk[i] = f2bf(fus_w[o * 64 + c]);
    }
}

// ------ Kernel C: fused depthwise(combined) conv + bf16-MFMA 1x1 conv ------
// Tile: 32 (W) x 8 (H) = 256 px; block = 256 threads = 4 waves.
// c chunked 2x32: LDS = s_dw 32 KB only (A-frags come prepacked from global).
// Phase 1 (per chunk): wave wv computes channels chunk*32 + wv*8 + {0..7},
//   each lane 4 consecutive px via 1 float4 + 2 guarded scalar loads per row,
//   stored into XOR-swizzled s_dw (write conflict-free, read 2-way = free).
// Phase 2 (per chunk): per wave 64(o) x 64(p) x 32(c) via 16 MFMA 16x16x32.
__global__ __launch_bounds__(256, 4) void fused_dw_mix_kernel(
    const float* __restrict__ x,        // [8][64][256][256]
    const float* __restrict__ wc,       // [8][64][9]
    const unsigned short* __restrict__ apk, // [2][4][64][8] bf16 A-fragments
    const float* __restrict__ fus_b,    // [64]
    float* __restrict__ out)            // [8][64][256][256]
{
    __shared__ float s_dw[32 * 256];    // [cl][swizzled p] 32 KB

    const int t  = threadIdx.x;
    const int b  = blockIdx.z;
    const int y0 = blockIdx.y * 8;
    const int x0 = blockIdx.x * 32;
    const int l    = t & 63;
    const int wv   = t >> 6;
    const int ln15 = l & 15;
    const int lh   = l >> 4;            // 0..3

    // phase-1 pixel assignment: lane l owns 4 px at linear tile index 4l
    const int py  = l >> 3;             // 0..7
    const int px4 = (l & 7) * 4;        // 0..28
    const int yy  = y0 + py;
    const int xx  = x0 + px4;
    const float* xb  = x + (size_t)b * (kC * kPlane);
    const float* wcb = wc + b * 576;
    const bool xlo = (xx > 0);
    const bool xhi = (xx < 252);

    f32x4 acc[4][4];
    #pragma unroll
    for (int i = 0; i < 4; ++i)
        #pragma unroll
        for (int j = 0; j < 4; ++j) acc[i][j] = (f32x4){0.f, 0.f, 0.f, 0.f};

    for (int chunk = 0; chunk < 2; ++chunk) {
        if (chunk) __syncthreads();     // previous phase-2 reads complete

        // ---------------- phase 1: depthwise conv into LDS ----------------
        #pragma unroll 2
        for (int k = 0; k < 8; ++k) {
            const int c  = chunk * 32 + wv * 8 + k;
            const int cl = wv * 8 + k;
            const float* w9 = wcb + __builtin_amdgcn_readfirstlane(c) * 9;
            const float* xc = xb + (size_t)c * kPlane;
            float a0 = 0.0f, a1 = 0.0f, a2 = 0.0f, a3 = 0.0f;
            #pragma unroll
            for (int r = -1; r <= 1; ++r) {
                const int Y = yy + r;
                if ((unsigned)Y < (unsigned)kH) {
                    const float* rp = xc + Y * kW + xx;
                    const float  lm = xlo ? rp[-1] : 0.0f;
                    const float4 M  = *(const float4*)rp;
                    const float  rm = xhi ? rp[4] : 0.0f;
                    const float w0 = w9[(r + 1) * 3 + 0];
                    const float w1 = w9[(r + 1) * 3 + 1];
                    const float w2 = w9[(r + 1) * 3 + 2];
                    a0 += w0 * lm  + w1 * M.x + w2 * M.y;
                    a1 += w0 * M.x + w1 * M.y + w2 * M.z;
                    a2 += w0 * M.y + w1 * M.z + w2 * M.w;
                    a3 += w0 * M.z + w1 * M.w + w2 * rm;
                }
            }
            float4 v; v.x = a0; v.y = a1; v.z = a2; v.w = a3;
            // swizzle: float idx = cl*256 + ((4l) ^ ((cl>>3)<<4)); cl>>3 == wv
            *(float4*)&s_dw[cl * 256 + ((4 * l) ^ (wv << 4))] = v;
        }
        __syncthreads();

        // ------------- phase 2: 16 MFMA 16x16x32 per wave -------------
        bf16x8 af[4];
        #pragma unroll
        for (int mb = 0; mb < 4; ++mb)
            af[mb] = *(const bf16x8*)(apk + (size_t)((chunk * 4 + mb) * 64 + l) * 8);

        #pragma unroll
        for (int nb = 0; nb < 4; ++nb) {
            const int p = wv * 64 + nb * 16 + ln15;
            const int pcol = p ^ (lh << 4);   // (cl>>3)&3 == lh for cl = lh*8+j
            float f[8];
            #pragma unroll
            for (int j = 0; j < 8; ++j)
                f[j] = s_dw[(lh * 8 + j) * 256 + pcol];
            bf16x8 bfr;
            #pragma unroll
            for (int j = 0; j < 8; ++j) bfr[j] = (short)f2bf(f[j]);
            #pragma unroll
            for (int mb = 0; mb < 4; ++mb)
                acc[mb][nb] = __builtin_amdgcn_mfma_f32_16x16x32_bf16(af[mb], bfr, acc[mb][nb], 0, 0, 0);
        }
    }

    // ---------------- epilogue: bias + scattered b32 stores ----------------
    // D layout: o = mb*16 + lh*4 + r, p = wv*64 + nb*16 + ln15
    float* ob = out + (size_t)(b * kC) * kPlane;
    #pragma unroll
    for (int mb = 0; mb < 4; ++mb) {
        #pragma unroll
        for (int nb = 0; nb < 4; ++nb) {
            const int p   = wv * 64 + nb * 16 + ln15;
            const int opy = p >> 5;
            const int opx = p & 31;
            float* pb = ob + (size_t)(y0 + opy) * kW + (x0 + opx);
            #pragma unroll
            for (int r = 0; r < 4; ++r) {
                const int o = mb * 16 + lh * 4 + r;
                pb[(size_t)o * kPlane] = acc[mb][nb][r] + fus_b[o];
            }
        }
    }
}

extern "C" void kernel_launch(void* const* d_in, const int* in_sizes, int n_in,
                              void* d_out, int out_size, void* d_ws, size_t ws_size,
                              hipStream_t stream) {
    const float* x     = (const float*)d_in[0];
    const float* idg_w = (const float*)d_in[1];
    const float* van_w = (const float*)d_in[2];
    const float* w1    = (const float*)d_in[3];
    const float* b1    = (const float*)d_in[4];
    const float* w2    = (const float*)d_in[5];
    const float* b2    = (const float*)d_in[6];
    const float* fw    = (const float*)d_in[7];
    const float* fb    = (const float*)d_in[8];
    float* out = (float*)d_out;

    float* wsf     = (float*)d_ws;
    float* partial = wsf;               // 2048 floats
    float* wcbuf   = wsf + 2048;        // 4608 floats
    unsigned short* apk = (unsigned short*)(wsf + 2048 + 4608); // 4096 ushort

    hipLaunchKernelGGL(pool_kernel, dim3(2048), dim3(256), 0, stream, x, partial);
    hipLaunchKernelGGL(att_wc_kernel, dim3(1), dim3(256), 0, stream,
                       partial, idg_w, van_w, w1, b1, w2, b2, fw, wcbuf, apk);
    hipLaunchKernelGGL(fused_dw_mix_kernel, dim3(kW / 32, kH / 8, 8), dim3(256), 0, stream,
                       x, wcbuf, apk, fb, out);
}